// Round 1
// baseline (120.194 us; speedup 1.0000x reference)
//
#include <hip/hip_runtime.h>
#include <math.h>

#define B_      32
#define NP1     2001
#define D_      512
#define R_      6
#define NROLES  190
#define NVERBS  504
#define VOCAB   2001
#define NREG    2000

#define NSPLIT  32          // n-splits per b -> 1024 blocks for K1
#define CHUNK   63          // ceil(2000/32)
#define PSTRIDE 3592        // 6*512 (SW) + 512 (rsum) + 8 (sumexp+pad)
#define WS_SR   0
#define WS_PART 8
#define WS_A    (8 + B_*NSPLIT*PSTRIDE)   // 3,678,216 floats; A is 192*512

__device__ __forceinline__ float fast_tanh(float x) {
    // tanh(x) = 1 - 2/(e^{2x}+1);  e^{2x} = 2^{x*2.885390}
    float e = exp2f(x * 2.885390082f);
    return 1.0f - 2.0f * __builtin_amdgcn_rcpf(e + 1.0f);
}
__device__ __forceinline__ float fast_exp(float x) {
    return exp2f(x * 1.442695041f);
}

// ---------------- K0: s_role[r] + ba  (tiny) ----------------
__global__ __launch_bounds__(1024) void k0_srole(
    const float* __restrict__ roles, const float* __restrict__ Wr,
    const float* __restrict__ br, const float* __restrict__ Wa,
    const float* __restrict__ ba, float* __restrict__ ws_sr) {
    const int tid = threadIdx.x;
    __shared__ float partial[4][NROLES];
    __shared__ float u_s[NROLES];
    const int q = tid >> 8;        // 0..3 -> d-range
    const int k = tid & 255;       // role-emb input index
    if (k < NROLES) {
        float s = 0.f;
        const int d0 = q * 128;
        #pragma unroll 8
        for (int d = 0; d < 128; ++d)
            s += Wr[(size_t)(d0 + d) * NROLES + k] * Wa[d0 + d];
        partial[q][k] = s;
    }
    __syncthreads();
    if (tid < NROLES)
        u_s[tid] = partial[0][tid] + partial[1][tid] + partial[2][tid] + partial[3][tid];
    __syncthreads();
    if (tid < 64) {
        float c0 = 0.f;
        for (int d = tid; d < D_; d += 64) c0 += Wa[d] * br[d];
        #pragma unroll
        for (int m = 1; m < 64; m <<= 1) c0 += __shfl_xor(c0, m, 64);
        for (int r = 0; r < R_; ++r) {
            float p = 0.f;
            for (int kk = tid; kk < NROLES; kk += 64) p += roles[r * NROLES + kk] * u_s[kk];
            #pragma unroll
            for (int m = 1; m < 64; m <<= 1) p += __shfl_xor(p, m, 64);
            if (tid == 0) ws_sr[r] = p + c0 + ba[0];
        }
    }
}

// ---------------- K1: fused main pass over regions ----------------
__global__ __launch_bounds__(256) void k1_main(
    const float* __restrict__ vs, const float* __restrict__ Wa,
    const float* __restrict__ ws_sr, float* __restrict__ part) {
    const int b     = blockIdx.x / NSPLIT;
    const int split = blockIdx.x % NSPLIT;
    const int tid   = threadIdx.x;
    const int lane  = tid & 63;
    const int wave  = tid >> 6;

    const float4 wvA = *reinterpret_cast<const float4*>(Wa + D_ + lane * 4);
    const float4 wvB = *reinterpret_cast<const float4*>(Wa + D_ + 256 + lane * 4);
    float sr[R_];
    #pragma unroll
    for (int r = 0; r < R_; ++r) sr[r] = ws_sr[r];

    float acc[R_][8];
    float rsum[8];
    float sume[R_];
    #pragma unroll
    for (int r = 0; r < R_; ++r) {
        sume[r] = 0.f;
        #pragma unroll
        for (int j = 0; j < 8; ++j) acc[r][j] = 0.f;
    }
    #pragma unroll
    for (int j = 0; j < 8; ++j) rsum[j] = 0.f;

    const float* base = vs + (size_t)b * (NP1 * D_) + D_;   // regions row 0
    const int n0 = split * CHUNK;
    const int n1 = min(n0 + CHUNK, NREG);

    int n = n0 + wave;
    // paired rows for ILP
    for (; n + 4 < n1; n += 8) {
        const float* rowA = base + (size_t)n * D_;
        const float* rowB = base + (size_t)(n + 4) * D_;
        float4 x0A = *reinterpret_cast<const float4*>(rowA + lane * 4);
        float4 x0B = *reinterpret_cast<const float4*>(rowA + 256 + lane * 4);
        float4 x1A = *reinterpret_cast<const float4*>(rowB + lane * 4);
        float4 x1B = *reinterpret_cast<const float4*>(rowB + 256 + lane * 4);
        float d0 = x0A.x*wvA.x + x0A.y*wvA.y + x0A.z*wvA.z + x0A.w*wvA.w
                 + x0B.x*wvB.x + x0B.y*wvB.y + x0B.z*wvB.z + x0B.w*wvB.w;
        float d1 = x1A.x*wvA.x + x1A.y*wvA.y + x1A.z*wvA.z + x1A.w*wvA.w
                 + x1B.x*wvB.x + x1B.y*wvB.y + x1B.z*wvB.z + x1B.w*wvB.w;
        #pragma unroll
        for (int m = 1; m < 64; m <<= 1) {
            d0 += __shfl_xor(d0, m, 64);
            d1 += __shfl_xor(d1, m, 64);
        }
        float xs0[8] = {x0A.x,x0A.y,x0A.z,x0A.w,x0B.x,x0B.y,x0B.z,x0B.w};
        float xs1[8] = {x1A.x,x1A.y,x1A.z,x1A.w,x1B.x,x1B.y,x1B.z,x1B.w};
        #pragma unroll
        for (int r = 0; r < R_; ++r) {
            float t0 = fast_tanh(sr[r] + d0);
            float t1 = fast_tanh(sr[r] + d1);
            sume[r] += fast_exp(t0) + fast_exp(t1);
            #pragma unroll
            for (int j = 0; j < 8; ++j) acc[r][j] += t0 * xs0[j] + t1 * xs1[j];
        }
        #pragma unroll
        for (int j = 0; j < 8; ++j) rsum[j] += xs0[j] + xs1[j];
    }
    if (n < n1) {
        const float* row = base + (size_t)n * D_;
        float4 xA = *reinterpret_cast<const float4*>(row + lane * 4);
        float4 xB = *reinterpret_cast<const float4*>(row + 256 + lane * 4);
        float d = xA.x*wvA.x + xA.y*wvA.y + xA.z*wvA.z + xA.w*wvA.w
                + xB.x*wvB.x + xB.y*wvB.y + xB.z*wvB.z + xB.w*wvB.w;
        #pragma unroll
        for (int m = 1; m < 64; m <<= 1) d += __shfl_xor(d, m, 64);
        float xs[8] = {xA.x,xA.y,xA.z,xA.w,xB.x,xB.y,xB.z,xB.w};
        #pragma unroll
        for (int r = 0; r < R_; ++r) {
            float t = fast_tanh(sr[r] + d);
            sume[r] += fast_exp(t);
            #pragma unroll
            for (int j = 0; j < 8; ++j) acc[r][j] += t * xs[j];
        }
        #pragma unroll
        for (int j = 0; j < 8; ++j) rsum[j] += xs[j];
    }

    // combine the 4 waves in LDS (deterministic, sequential)
    __shared__ __align__(16) float ls[3584];
    __shared__ float lse_[4][R_];
    for (int w = 0; w < 4; ++w) {
        if (wave == w) {
            #pragma unroll
            for (int j = 0; j < 8; ++j) {
                const int dd = (j < 4) ? (lane * 4 + j) : (256 + lane * 4 + (j - 4));
                if (w == 0) {
                    #pragma unroll
                    for (int r = 0; r < R_; ++r) ls[r * D_ + dd] = acc[r][j];
                    ls[6 * D_ + dd] = rsum[j];
                } else {
                    #pragma unroll
                    for (int r = 0; r < R_; ++r) ls[r * D_ + dd] += acc[r][j];
                    ls[6 * D_ + dd] += rsum[j];
                }
            }
            if (lane == 0) {
                #pragma unroll
                for (int r = 0; r < R_; ++r) lse_[w][r] = sume[r];
            }
        }
        __syncthreads();
    }
    float* dst = part + (size_t)(b * NSPLIT + split) * PSTRIDE;
    for (int i = tid; i < 3584 / 4; i += 256)
        reinterpret_cast<float4*>(dst)[i] = reinterpret_cast<const float4*>(ls)[i];
    if (tid < R_)
        dst[3584 + tid] = lse_[0][tid] + lse_[1][tid] + lse_[2][tid] + lse_[3][tid];
}

// ---------------- K2: reduce partials -> relu(label_embed) ----------------
__global__ __launch_bounds__(256) void k2_reduce(
    const float* __restrict__ part, float* __restrict__ A) {
    const int b = blockIdx.x;
    const int chunk = blockIdx.y;         // 8 chunks of 64 d
    const int t = threadIdx.x;
    const int dl = t & 63;
    const int qg = t >> 6;                // 4 groups of 8 partials
    const int d = chunk * 64 + dl;
    const float* pb = part + (size_t)b * NSPLIT * PSTRIDE;

    float s[7] = {0.f, 0.f, 0.f, 0.f, 0.f, 0.f, 0.f};
    for (int q = qg * 8; q < qg * 8 + 8; ++q) {
        const float* p = pb + (size_t)q * PSTRIDE;
        #pragma unroll
        for (int r = 0; r < R_; ++r) s[r] += p[r * D_ + d];
        s[6] += p[6 * D_ + d];
    }
    __shared__ float red[4][7][64];
    #pragma unroll
    for (int i = 0; i < 7; ++i) red[qg][i][dl] = s[i];
    __shared__ float lse_s[R_];
    if (t < R_) {
        float se = 0.f;
        for (int q = 0; q < NSPLIT; ++q) se += pb[(size_t)q * PSTRIDE + 3584 + t];
        lse_s[t] = logf(se);
    }
    __syncthreads();
    if (t < 64) {
        float rs = red[0][6][dl] + red[1][6][dl] + red[2][6][dl] + red[3][6][dl];
        #pragma unroll
        for (int r = 0; r < R_; ++r) {
            float sw = red[0][r][dl] + red[1][r][dl] + red[2][r][dl] + red[3][r][dl];
            A[((size_t)b * R_ + r) * D_ + d] = fmaxf(sw - lse_s[r] * rs, 0.f);
        }
    }
}

// ---------------- K3: role_label_predict GEMM (192 x 2001 x 512) ----------------
#define BM 32
#define BN 64
#define KC 64
__global__ __launch_bounds__(256) void k3_gemm(
    const float* __restrict__ A, const float* __restrict__ Wl,
    const float* __restrict__ bl, float* __restrict__ out) {
    const int t  = threadIdx.x;
    const int tx = t & 15;           // col group (4 cols)
    const int ty = t >> 4;           // row group (2 rows)
    const int m0 = blockIdx.y * BM;
    const int v0 = blockIdx.x * BN;
    __shared__ __align__(16) float As[KC][34];   // transposed [k][m]
    __shared__ __align__(16) float Bs[KC][68];   // transposed [k][v]
    float acc[2][4] = {{0.f,0.f,0.f,0.f},{0.f,0.f,0.f,0.f}};

    for (int k0 = 0; k0 < D_; k0 += KC) {
        __syncthreads();
        #pragma unroll
        for (int i = 0; i < 2; ++i) {
            int idx = t + i * 256;                // 0..511
            int m = idx >> 4;                     // 0..31
            int kq = (idx & 15) << 2;             // 0..60
            float4 a4 = *reinterpret_cast<const float4*>(A + (size_t)(m0 + m) * D_ + k0 + kq);
            As[kq + 0][m] = a4.x; As[kq + 1][m] = a4.y;
            As[kq + 2][m] = a4.z; As[kq + 3][m] = a4.w;
        }
        #pragma unroll
        for (int i = 0; i < 4; ++i) {
            int idx = t + i * 256;                // 0..1023
            int v = idx >> 4;                     // 0..63
            int kq = (idx & 15) << 2;
            float4 b4 = make_float4(0.f, 0.f, 0.f, 0.f);
            if (v0 + v < VOCAB)
                b4 = *reinterpret_cast<const float4*>(Wl + (size_t)(v0 + v) * D_ + k0 + kq);
            Bs[kq + 0][v] = b4.x; Bs[kq + 1][v] = b4.y;
            Bs[kq + 2][v] = b4.z; Bs[kq + 3][v] = b4.w;
        }
        __syncthreads();
        #pragma unroll 8
        for (int k = 0; k < KC; ++k) {
            float2 a2 = *reinterpret_cast<const float2*>(&As[k][ty * 2]);
            float4 b4 = *reinterpret_cast<const float4*>(&Bs[k][tx * 4]);
            acc[0][0] += a2.x * b4.x; acc[0][1] += a2.x * b4.y;
            acc[0][2] += a2.x * b4.z; acc[0][3] += a2.x * b4.w;
            acc[1][0] += a2.y * b4.x; acc[1][1] += a2.y * b4.y;
            acc[1][2] += a2.y * b4.z; acc[1][3] += a2.y * b4.w;
        }
    }
    #pragma unroll
    for (int i = 0; i < 2; ++i) {
        int m = m0 + ty * 2 + i;
        #pragma unroll
        for (int c = 0; c < 4; ++c) {
            int v = v0 + tx * 4 + c;
            if (v < VOCAB) out[(size_t)m * VOCAB + v] = acc[i][c] + bl[v];
        }
    }
}

// ---------------- K4: verb head ----------------
__global__ __launch_bounds__(256) void k4_verb(
    const float* __restrict__ vs, const float* __restrict__ Wv,
    const float* __restrict__ bv, float* __restrict__ out) {
    const int b = blockIdx.x;
    const int tid = threadIdx.x;
    __shared__ __align__(16) float a_s[D_];
    #pragma unroll
    for (int i = 0; i < 2; ++i) {
        int d = tid + i * 256;
        a_s[d] = fmaxf(vs[(size_t)b * (NP1 * D_) + d], 0.f);
    }
    __syncthreads();
    for (int v = tid; v < NVERBS; v += 256) {
        const float* wrow = Wv + (size_t)v * D_;
        float s = 0.f;
        #pragma unroll 4
        for (int k = 0; k < D_; k += 4) {
            float4 w4 = *reinterpret_cast<const float4*>(wrow + k);
            s += a_s[k] * w4.x + a_s[k + 1] * w4.y + a_s[k + 2] * w4.z + a_s[k + 3] * w4.w;
        }
        out[b * NVERBS + v] = s + bv[v];
    }
}

extern "C" void kernel_launch(void* const* d_in, const int* in_sizes, int n_in,
                              void* d_out, int out_size, void* d_ws, size_t ws_size,
                              hipStream_t stream) {
    const float* vs    = (const float*)d_in[0];
    const float* roles = (const float*)d_in[1];
    const float* Wr    = (const float*)d_in[2];
    const float* br    = (const float*)d_in[3];
    const float* Wa    = (const float*)d_in[4];
    const float* ba    = (const float*)d_in[5];
    const float* Wv    = (const float*)d_in[6];
    const float* bv    = (const float*)d_in[7];
    const float* Wl    = (const float*)d_in[8];
    const float* bl    = (const float*)d_in[9];

    float* out_verb = (float*)d_out;                    // [32][504]
    float* out_role = (float*)d_out + B_ * NVERBS;      // [32][6][2001]
    float* ws       = (float*)d_ws;
    float* ws_sr    = ws + WS_SR;
    float* ws_part  = ws + WS_PART;
    float* ws_A     = ws + WS_A;

    k0_srole<<<dim3(1), dim3(1024), 0, stream>>>(roles, Wr, br, Wa, ba, ws_sr);
    k1_main<<<dim3(B_ * NSPLIT), dim3(256), 0, stream>>>(vs, Wa, ws_sr, ws_part);
    k2_reduce<<<dim3(B_, 8), dim3(256), 0, stream>>>(ws_part, ws_A);
    k3_gemm<<<dim3(32, 6), dim3(256), 0, stream>>>(ws_A, Wl, bl, out_role);
    k4_verb<<<dim3(B_), dim3(256), 0, stream>>>(vs, Wv, bv, out_verb);
}